// Round 2
// baseline (251.778 us; speedup 1.0000x reference)
//
#include <hip/hip_runtime.h>

// Gather + ragged segment XOR reduction.
//   entries [N,5] i32, blocks/offsets [T] i32, starts/sizes [H] i32, bs scalar.
//   out [H,5] i32.
//
// R1 finding: 5 scalar dword gathers/token -> 5 divergent L1 transactions/token;
// kernel is gather-transaction-bound (3.7 TB/s, VALUBusy 18%).
// R2: pre-pass pads entries to 32 B rows (16B-aligned) in d_ws; gather becomes
// dwordx4 + dword = 2 transactions/token. Falls back to 5-dword path if ws too small.

__global__ __launch_bounds__(256) void pad_entries(
    const int* __restrict__ e, int* __restrict__ p, long n8)
{
    long i = (long)blockIdx.x * blockDim.x + threadIdx.x;
    if (i >= n8) return;
    long r = i >> 3;
    int  c = (int)(i & 7);
    p[i] = (c < 5) ? e[r * 5 + c] : 0;
}

__global__ __launch_bounds__(256) void hint_xor_wave_padded(
    const int* __restrict__ padded,   // [N,8] int32, rows 32B-aligned
    const int* __restrict__ blocks,
    const int* __restrict__ offsets,
    const int* __restrict__ starts,
    const int* __restrict__ sizes,
    const int* __restrict__ bs_ptr,
    int* __restrict__ out,
    int H, int N)
{
    const int gtid = blockIdx.x * blockDim.x + threadIdx.x;
    const int hint = gtid >> 6;
    const int lane = gtid & 63;
    if (hint >= H) return;

    const int start = starts[hint];
    const int size  = sizes[hint];
    const int bs    = bs_ptr[0];

    int a0 = 0, a1 = 0, a2 = 0, a3 = 0, a4 = 0;

    for (int j = lane; j < size; j += 64) {
        int idx = blocks[start + j] * bs + offsets[start + j];
        idx = min(max(idx, 0), N - 1);
        const int* row = padded + ((size_t)idx << 3);
        int4 v = *(const int4*)row;     // dwordx4: comps 0-3, one L1 line
        int  f = row[4];                // dword:   comp 4, same line
        a0 ^= v.x; a1 ^= v.y; a2 ^= v.z; a3 ^= v.w; a4 ^= f;
    }

    #pragma unroll
    for (int m = 1; m < 64; m <<= 1) {
        a0 ^= __shfl_xor(a0, m);
        a1 ^= __shfl_xor(a1, m);
        a2 ^= __shfl_xor(a2, m);
        a3 ^= __shfl_xor(a3, m);
        a4 ^= __shfl_xor(a4, m);
    }

    if (lane == 0) {
        int* o = out + (size_t)hint * 5;
        o[0] = a0; o[1] = a1; o[2] = a2; o[3] = a3; o[4] = a4;
    }
}

// R1 fallback (5-dword gather) in case ws_size < N*32 bytes.
__global__ __launch_bounds__(256) void hint_xor_wave(
    const int* __restrict__ entries,
    const int* __restrict__ blocks,
    const int* __restrict__ offsets,
    const int* __restrict__ starts,
    const int* __restrict__ sizes,
    const int* __restrict__ bs_ptr,
    int* __restrict__ out,
    int H, int N)
{
    const int gtid = blockIdx.x * blockDim.x + threadIdx.x;
    const int hint = gtid >> 6;
    const int lane = gtid & 63;
    if (hint >= H) return;

    const int start = starts[hint];
    const int size  = sizes[hint];
    const int bs    = bs_ptr[0];

    int a0 = 0, a1 = 0, a2 = 0, a3 = 0, a4 = 0;
    for (int j = lane; j < size; j += 64) {
        int idx = blocks[start + j] * bs + offsets[start + j];
        idx = min(max(idx, 0), N - 1);
        const int* row = entries + (size_t)idx * 5;
        a0 ^= row[0]; a1 ^= row[1]; a2 ^= row[2]; a3 ^= row[3]; a4 ^= row[4];
    }
    #pragma unroll
    for (int m = 1; m < 64; m <<= 1) {
        a0 ^= __shfl_xor(a0, m);
        a1 ^= __shfl_xor(a1, m);
        a2 ^= __shfl_xor(a2, m);
        a3 ^= __shfl_xor(a3, m);
        a4 ^= __shfl_xor(a4, m);
    }
    if (lane == 0) {
        int* o = out + (size_t)hint * 5;
        o[0] = a0; o[1] = a1; o[2] = a2; o[3] = a3; o[4] = a4;
    }
}

extern "C" void kernel_launch(void* const* d_in, const int* in_sizes, int n_in,
                              void* d_out, int out_size, void* d_ws, size_t ws_size,
                              hipStream_t stream) {
    const int* entries = (const int*)d_in[0];
    const int* blocks  = (const int*)d_in[1];
    const int* offsets = (const int*)d_in[2];
    const int* starts  = (const int*)d_in[3];
    const int* sizes   = (const int*)d_in[4];
    const int* bs      = (const int*)d_in[5];
    int* out = (int*)d_out;

    const int H = in_sizes[3];
    const int N = in_sizes[0] / 5;

    const long total_threads = (long)H * 64;
    const int block = 256;
    const int grid = (int)((total_threads + block - 1) / block);

    const size_t pad_bytes = (size_t)N * 8 * sizeof(int);
    if (ws_size >= pad_bytes) {
        int* padded = (int*)d_ws;
        const long n8 = (long)N * 8;
        const int pgrid = (int)((n8 + block - 1) / block);
        hipLaunchKernelGGL(pad_entries, dim3(pgrid), dim3(block), 0, stream,
                           entries, padded, n8);
        hipLaunchKernelGGL(hint_xor_wave_padded, dim3(grid), dim3(block), 0, stream,
                           padded, blocks, offsets, starts, sizes, bs, out, H, N);
    } else {
        hipLaunchKernelGGL(hint_xor_wave, dim3(grid), dim3(block), 0, stream,
                           entries, blocks, offsets, starts, sizes, bs, out, H, N);
    }
}